// Round 1
// baseline (285.365 us; speedup 1.0000x reference)
//
#include <hip/hip_runtime.h>

#define C_DIM 512
#define N_PIX 1024
#define B_DIM 8
#define NHEAD 8
#define HDIM 64
#define NGRP 8
#define CG 64
#define EPSF 1e-5f

typedef __bf16 bf16x8_t __attribute__((ext_vector_type(8)));
typedef __bf16 bf16x4_t __attribute__((ext_vector_type(4)));
typedef float  f32x4_t  __attribute__((ext_vector_type(4)));

__device__ __forceinline__ __bf16 f2b(float f) {
  // round-to-nearest-even fp32 -> bf16 (no NaN inputs in this workload)
  unsigned int u = __builtin_bit_cast(unsigned int, f);
  u += 0x7fffu + ((u >> 16) & 1u);
  unsigned short s = (unsigned short)(u >> 16);
  return __builtin_bit_cast(__bf16, s);
}

__device__ __forceinline__ void async16(const void* g, void* l) {
  __builtin_amdgcn_global_load_lds((const __attribute__((address_space(1))) void*)g,
                                   (__attribute__((address_space(3))) void*)l, 16, 0, 0);
}

// ---------------- weight fp32 -> bf16 ----------------
__global__ __launch_bounds__(256) void convert_w_kernel(
    const float* __restrict__ qw, const float* __restrict__ kw,
    const float* __restrict__ vw, const float* __restrict__ pw,
    __bf16* __restrict__ wb)
{
  int idx = blockIdx.x * 256 + threadIdx.x;          // 262144 threads
  int mat = idx >> 16;
  int off = (idx & 65535) * 4;
  const float* src = (mat == 0) ? qw : (mat == 1) ? kw : (mat == 2) ? vw : pw;
  float4 v = *(const float4*)(src + off);
  bf16x4_t pk;
  pk[0] = f2b(v.x); pk[1] = f2b(v.y); pk[2] = f2b(v.z); pk[3] = f2b(v.w);
  *(bf16x4_t*)(wb + mat * (512 * 512) + off) = pk;
}

// ---------------- GroupNorm -> xnT bf16 [B][N][C] ----------------
__global__ __launch_bounds__(256) void groupnorm_kernel(
    const float* __restrict__ x, const float* __restrict__ gw,
    const float* __restrict__ gb, __bf16* __restrict__ xnT)
{
  const int b = blockIdx.x >> 3, g = blockIdx.x & 7;
  const float* xp = x + ((size_t)b * C_DIM + g * CG) * N_PIX;
  float s = 0.f, s2 = 0.f;
  for (int i4 = threadIdx.x; i4 < (CG * N_PIX) / 4; i4 += 256) {
    float4 v = ((const float4*)xp)[i4];
    s += v.x + v.y + v.z + v.w;
    s2 += v.x * v.x + v.y * v.y + v.z * v.z + v.w * v.w;
  }
#pragma unroll
  for (int off = 32; off; off >>= 1) {
    s  += __shfl_xor(s, off, 64);
    s2 += __shfl_xor(s2, off, 64);
  }
  __shared__ float red[8];
  const int lane = threadIdx.x & 63, wv = threadIdx.x >> 6;
  if (lane == 0) { red[wv] = s; red[4 + wv] = s2; }
  __syncthreads();
  s  = red[0] + red[1] + red[2] + red[3];
  s2 = red[4] + red[5] + red[6] + red[7];
  const float inv = 1.f / (float)(CG * N_PIX);
  const float mu = s * inv;
  const float var = s2 * inv - mu * mu;
  const float rstd = rsqrtf(var + EPSF);
  for (int i = threadIdx.x; i < CG * N_PIX; i += 256) {
    const int c = i >> 10, n = i & 1023;
    const float wgt = gw[g * CG + c], bia = gb[g * CG + c];
    float v = (xp[i] - mu) * rstd * wgt + bia;
    xnT[((size_t)b * N_PIX + n) * C_DIM + g * CG + c] = f2b(v);
  }
}

// ---------------- shared 128x128 gemm_bt core (K=512, lda=ldb=512) ----------------
__device__ __forceinline__ void gemm_core_128(
    const __bf16* __restrict__ A, const __bf16* __restrict__ B,
    __bf16* As, __bf16* Bs, f32x4_t acc[4][4])
{
  const int tid  = threadIdx.x;
  const int lane = tid & 63;
  const int wv   = tid >> 6;
  const int quad = lane >> 4;
  const int l16  = lane & 15;
  const int wm = (wv >> 1) * 64;
  const int wn = (wv & 1) * 64;

  f32x4_t zero = {0.f, 0.f, 0.f, 0.f};
#pragma unroll
  for (int i = 0; i < 4; i++)
#pragma unroll
    for (int j = 0; j < 4; j++) acc[i][j] = zero;

  const int chb0 = wv * 64;          // wave-uniform chunk bases
  const int chb1 = 256 + wv * 64;
  const int ch0 = chb0 + lane, ch1 = chb1 + lane;
  const int r0 = ch0 >> 2, k0 = (ch0 & 3) * 8;
  const int r1 = ch1 >> 2, k1 = (ch1 & 3) * 8;

  for (int kt = 0; kt < 512; kt += 32) {
    async16(A + (size_t)r0 * 512 + kt + k0, As + chb0 * 8);
    async16(A + (size_t)r1 * 512 + kt + k1, As + chb1 * 8);
    async16(B + (size_t)r0 * 512 + kt + k0, Bs + chb0 * 8);
    async16(B + (size_t)r1 * 512 + kt + k1, Bs + chb1 * 8);
    __builtin_amdgcn_s_waitcnt(0);
    __syncthreads();
    bf16x8_t af[4], bfr[4];
#pragma unroll
    for (int i = 0; i < 4; i++)
      af[i] = *(const bf16x8_t*)(As + (wm + i * 16 + l16) * 32 + quad * 8);
#pragma unroll
    for (int j = 0; j < 4; j++)
      bfr[j] = *(const bf16x8_t*)(Bs + (wn + j * 16 + l16) * 32 + quad * 8);
#pragma unroll
    for (int i = 0; i < 4; i++)
#pragma unroll
      for (int j = 0; j < 4; j++)
        acc[i][j] = __builtin_amdgcn_mfma_f32_16x16x32_bf16(af[i], bfr[j], acc[i][j], 0, 0, 0);
    __syncthreads();
  }
}

// ---------------- QKV gemm: Q,K -> [b][n][c] bf16 ; V -> [b][c][n] bf16 ----------------
__global__ __launch_bounds__(256) void gemm_qkv_kernel(
    const __bf16* __restrict__ wqkv, const float* __restrict__ qb,
    const float* __restrict__ kb, const float* __restrict__ vb,
    const __bf16* __restrict__ xnT,
    __bf16* __restrict__ qT, __bf16* __restrict__ kT, __bf16* __restrict__ vbuf)
{
  __shared__ __align__(16) __bf16 As[128 * 32];
  __shared__ __align__(16) __bf16 Bs[128 * 32];
  const int z = blockIdx.z, b = z / 3, mat = z % 3;
  const int m0 = blockIdx.y * 128, n0 = blockIdx.x * 128;
  const __bf16* A = wqkv + (size_t)mat * (512 * 512) + (size_t)m0 * 512;
  const __bf16* B = xnT + ((size_t)b * N_PIX + n0) * 512;
  f32x4_t acc[4][4];
  gemm_core_128(A, B, As, Bs, acc);

  const int tid = threadIdx.x, lane = tid & 63, wv = tid >> 6;
  const int quad = lane >> 4, l16 = lane & 15;
  const int wm = (wv >> 1) * 64, wn = (wv & 1) * 64;
  const float* bias = (mat == 0) ? qb : (mat == 1) ? kb : vb;

  if (mat < 2) {
    __bf16* dst = (mat == 0) ? qT : kT;
#pragma unroll
    for (int i = 0; i < 4; i++) {
      const int o = m0 + wm + i * 16 + quad * 4;
      float b0 = bias[o], b1 = bias[o + 1], b2 = bias[o + 2], b3 = bias[o + 3];
#pragma unroll
      for (int j = 0; j < 4; j++) {
        const int n = n0 + wn + j * 16 + l16;
        bf16x4_t pk;
        pk[0] = f2b(acc[i][j][0] + b0);
        pk[1] = f2b(acc[i][j][1] + b1);
        pk[2] = f2b(acc[i][j][2] + b2);
        pk[3] = f2b(acc[i][j][3] + b3);
        *(bf16x4_t*)(dst + ((size_t)b * N_PIX + n) * 512 + o) = pk;
      }
    }
  } else {
#pragma unroll
    for (int i = 0; i < 4; i++) {
      const int o = m0 + wm + i * 16 + quad * 4;
#pragma unroll
      for (int j = 0; j < 4; j++) {
        const int n = n0 + wn + j * 16 + l16;
#pragma unroll
        for (int r = 0; r < 4; r++)
          vbuf[((size_t)b * 512 + o + r) * N_PIX + n] = f2b(acc[i][j][r] + bias[o + r]);
      }
    }
  }
}

// ---------------- flash attention: BQ=64 per block, 4 waves x 16 q-rows ----------------
__global__ __launch_bounds__(256) void attn_kernel(
    const __bf16* __restrict__ qT, const __bf16* __restrict__ kT,
    const __bf16* __restrict__ vbuf, __bf16* __restrict__ aT)
{
  __shared__ __align__(16) __bf16 Qs[64 * 72];
  __shared__ __align__(16) __bf16 Ks[128 * 72];
  __shared__ __align__(16) __bf16 Vs[64 * 136];   // V^T tile [c][m]
  __shared__ __align__(16) __bf16 Ps[64 * 136];   // P tile [n][m], per-wave rows
  const int nb = blockIdx.x, h = blockIdx.y, b = blockIdx.z;
  const int tid = threadIdx.x, lane = tid & 63, wv = tid >> 6;
  const int quad = lane >> 4, l16 = lane & 15;
  const int n0 = nb * 64;
  const __bf16* qp = qT + ((size_t)b * N_PIX + n0) * 512 + h * 64;
  const __bf16* kp = kT + ((size_t)b * N_PIX) * 512 + h * 64;
  const __bf16* vp = vbuf + ((size_t)b * 512 + h * 64) * N_PIX;

  for (int cq = tid; cq < 512; cq += 256) {
    int r = cq >> 3, kc = (cq & 7) * 8;
    *(bf16x8_t*)(Qs + r * 72 + kc) = *(const bf16x8_t*)(qp + (size_t)r * 512 + kc);
  }
  __syncthreads();
  bf16x8_t qf[2];
  qf[0] = *(const bf16x8_t*)(Qs + (wv * 16 + l16) * 72 + quad * 8);
  qf[1] = *(const bf16x8_t*)(Qs + (wv * 16 + l16) * 72 + 32 + quad * 8);

  f32x4_t zero = {0.f, 0.f, 0.f, 0.f};
  float mrow[4], lrow[4];
  f32x4_t oacc[4];
#pragma unroll
  for (int r = 0; r < 4; r++) { mrow[r] = -1e30f; lrow[r] = 0.f; }
#pragma unroll
  for (int jc = 0; jc < 4; jc++) oacc[jc] = zero;

  const float scale = 0.125f;   // HD^-0.5

  for (int mt = 0; mt < N_PIX; mt += 128) {
    __syncthreads();
    for (int cq = tid; cq < 1024; cq += 256) {
      int r = cq >> 3, kc = (cq & 7) * 8;
      *(bf16x8_t*)(Ks + r * 72 + kc) = *(const bf16x8_t*)(kp + (size_t)(mt + r) * 512 + kc);
    }
    for (int cv = tid; cv < 1024; cv += 256) {
      int c = cv >> 4, mc = (cv & 15) * 8;
      *(bf16x8_t*)(Vs + c * 136 + mc) = *(const bf16x8_t*)(vp + (size_t)c * N_PIX + mt + mc);
    }
    __syncthreads();

    // S = Q K^T : this wave's 16 rows x 128 cols
    f32x4_t sacc[8];
#pragma unroll
    for (int j = 0; j < 8; j++) sacc[j] = zero;
#pragma unroll
    for (int j = 0; j < 8; j++) {
      bf16x8_t kf0 = *(const bf16x8_t*)(Ks + (j * 16 + l16) * 72 + quad * 8);
      bf16x8_t kf1 = *(const bf16x8_t*)(Ks + (j * 16 + l16) * 72 + 32 + quad * 8);
      sacc[j] = __builtin_amdgcn_mfma_f32_16x16x32_bf16(qf[0], kf0, sacc[j], 0, 0, 0);
      sacc[j] = __builtin_amdgcn_mfma_f32_16x16x32_bf16(qf[1], kf1, sacc[j], 0, 0, 0);
    }
#pragma unroll
    for (int j = 0; j < 8; j++) sacc[j] *= scale;

    // online softmax: rows owned by this lane's quad (row = quad*4 + r)
    float alpha[4];
#pragma unroll
    for (int r = 0; r < 4; r++) {
      float vm = sacc[0][r];
#pragma unroll
      for (int j = 1; j < 8; j++) vm = fmaxf(vm, sacc[j][r]);
      vm = fmaxf(vm, __shfl_xor(vm, 1, 64));
      vm = fmaxf(vm, __shfl_xor(vm, 2, 64));
      vm = fmaxf(vm, __shfl_xor(vm, 4, 64));
      vm = fmaxf(vm, __shfl_xor(vm, 8, 64));
      float mnew = fmaxf(mrow[r], vm);
      alpha[r] = __expf(mrow[r] - mnew);
      mrow[r] = mnew;
    }
    float rs[4] = {0.f, 0.f, 0.f, 0.f};
#pragma unroll
    for (int j = 0; j < 8; j++) {
#pragma unroll
      for (int r = 0; r < 4; r++) {
        float p = __expf(sacc[j][r] - mrow[r]);
        rs[r] += p;
        Ps[(wv * 16 + quad * 4 + r) * 136 + j * 16 + l16] = f2b(p);
      }
    }
#pragma unroll
    for (int r = 0; r < 4; r++) {
      rs[r] += __shfl_xor(rs[r], 1, 64);
      rs[r] += __shfl_xor(rs[r], 2, 64);
      rs[r] += __shfl_xor(rs[r], 4, 64);
      rs[r] += __shfl_xor(rs[r], 8, 64);
      lrow[r] = lrow[r] * alpha[r] + rs[r];
    }
#pragma unroll
    for (int jc = 0; jc < 4; jc++)
#pragma unroll
      for (int r = 0; r < 4; r++) oacc[jc][r] *= alpha[r];

    asm volatile("s_waitcnt lgkmcnt(0)" ::: "memory");  // Ps writes -> reads (same wave)

    // O += P V  (P as A-operand from LDS, V^T rows as B-operand)
#pragma unroll
    for (int kk = 0; kk < 4; kk++) {
      bf16x8_t pf = *(const bf16x8_t*)(Ps + (wv * 16 + l16) * 136 + kk * 32 + quad * 8);
#pragma unroll
      for (int jc = 0; jc < 4; jc++) {
        bf16x8_t vf = *(const bf16x8_t*)(Vs + (jc * 16 + l16) * 136 + kk * 32 + quad * 8);
        oacc[jc] = __builtin_amdgcn_mfma_f32_16x16x32_bf16(pf, vf, oacc[jc], 0, 0, 0);
      }
    }
  }

#pragma unroll
  for (int jc = 0; jc < 4; jc++) {
#pragma unroll
    for (int r = 0; r < 4; r++) {
      int n = n0 + wv * 16 + quad * 4 + r;
      int c = h * 64 + jc * 16 + l16;
      aT[((size_t)b * N_PIX + n) * 512 + c] = f2b(oacc[jc][r] / lrow[r]);
    }
  }
}

// ---------------- proj gemm + bias + residual -> fp32 out [b][c][n] ----------------
__global__ __launch_bounds__(256) void gemm_proj_kernel(
    const __bf16* __restrict__ wp, const float* __restrict__ pb,
    const __bf16* __restrict__ aT, const float* __restrict__ x,
    float* __restrict__ out)
{
  __shared__ __align__(16) __bf16 As[128 * 32];
  __shared__ __align__(16) __bf16 Bs[128 * 32];
  const int b = blockIdx.z;
  const int m0 = blockIdx.y * 128, n0 = blockIdx.x * 128;
  const __bf16* A = wp + (size_t)m0 * 512;
  const __bf16* B = aT + ((size_t)b * N_PIX + n0) * 512;
  f32x4_t acc[4][4];
  gemm_core_128(A, B, As, Bs, acc);
  const int tid = threadIdx.x, lane = tid & 63, wv = tid >> 6;
  const int quad = lane >> 4, l16 = lane & 15;
  const int wm = (wv >> 1) * 64, wn = (wv & 1) * 64;
#pragma unroll
  for (int i = 0; i < 4; i++) {
    const int o = m0 + wm + i * 16 + quad * 4;
#pragma unroll
    for (int j = 0; j < 4; j++) {
      const int n = n0 + wn + j * 16 + l16;
#pragma unroll
      for (int r = 0; r < 4; r++) {
        size_t idx = ((size_t)b * 512 + o + r) * N_PIX + n;
        out[idx] = acc[i][j][r] + pb[o + r] + x[idx];
      }
    }
  }
}

extern "C" void kernel_launch(void* const* d_in, const int* in_sizes, int n_in,
                              void* d_out, int out_size, void* d_ws, size_t ws_size,
                              hipStream_t stream)
{
  (void)in_sizes; (void)n_in; (void)out_size; (void)ws_size;
  const float* x   = (const float*)d_in[0];
  const float* gnw = (const float*)d_in[1];
  const float* gnb = (const float*)d_in[2];
  const float* qw  = (const float*)d_in[3];
  const float* qb  = (const float*)d_in[4];
  const float* kw  = (const float*)d_in[5];
  const float* kb  = (const float*)d_in[6];
  const float* vw  = (const float*)d_in[7];
  const float* vb  = (const float*)d_in[8];
  const float* pw  = (const float*)d_in[9];
  const float* pb  = (const float*)d_in[10];
  float* out = (float*)d_out;

  char* ws = (char*)d_ws;
  __bf16* wb  = (__bf16*)(ws);                         // 2 MB: qw,kw,vw,pw bf16
  __bf16* xnT = (__bf16*)(ws + (size_t)(2  << 20));    // 8 MB
  __bf16* qTb = (__bf16*)(ws + (size_t)(10 << 20));    // 8 MB
  __bf16* kTb = (__bf16*)(ws + (size_t)(18 << 20));    // 8 MB
  __bf16* vbf = (__bf16*)(ws + (size_t)(26 << 20));    // 8 MB
  __bf16* aT  = (__bf16*)(ws + (size_t)(34 << 20));    // 8 MB (ends 42 MB)

  hipLaunchKernelGGL(convert_w_kernel, dim3(1024), dim3(256), 0, stream, qw, kw, vw, pw, wb);
  hipLaunchKernelGGL(groupnorm_kernel, dim3(64), dim3(256), 0, stream, x, gnw, gnb, xnT);
  hipLaunchKernelGGL(gemm_qkv_kernel, dim3(8, 4, 24), dim3(256), 0, stream,
                     wb, qb, kb, vb, xnT, qTb, kTb, vbf);
  hipLaunchKernelGGL(attn_kernel, dim3(16, 8, 8), dim3(256), 0, stream, qTb, kTb, vbf, aT);
  hipLaunchKernelGGL(gemm_proj_kernel, dim3(8, 4, 8), dim3(256), 0, stream,
                     wb + (size_t)3 * 512 * 512, pb, aT, x, out);
}

// Round 2
// 216.059 us; speedup vs baseline: 1.3208x; 1.3208x over previous
//
#include <hip/hip_runtime.h>

#define C_DIM 512
#define N_PIX 1024
#define B_DIM 8
#define NHEAD 8
#define HDIM 64
#define NGRP 8
#define CG 64
#define EPSF 1e-5f

typedef __bf16 bf16x8_t __attribute__((ext_vector_type(8)));
typedef __bf16 bf16x4_t __attribute__((ext_vector_type(4)));
typedef float  f32x4_t  __attribute__((ext_vector_type(4)));

__device__ __forceinline__ __bf16 f2b(float f) {
  unsigned int u = __builtin_bit_cast(unsigned int, f);
  u += 0x7fffu + ((u >> 16) & 1u);
  unsigned short s = (unsigned short)(u >> 16);
  return __builtin_bit_cast(__bf16, s);
}

__device__ __forceinline__ void async16(const void* g, void* l) {
  __builtin_amdgcn_global_load_lds((const __attribute__((address_space(1))) void*)g,
                                   (__attribute__((address_space(3))) void*)l, 16, 0, 0);
}

// ---------------- weight fp32 -> bf16 ----------------
__global__ __launch_bounds__(256) void convert_w_kernel(
    const float* __restrict__ qw, const float* __restrict__ kw,
    const float* __restrict__ vw, const float* __restrict__ pw,
    __bf16* __restrict__ wb)
{
  int idx = blockIdx.x * 256 + threadIdx.x;
  int mat = idx >> 16;
  int off = (idx & 65535) * 4;
  const float* src = (mat == 0) ? qw : (mat == 1) ? kw : (mat == 2) ? vw : pw;
  float4 v = *(const float4*)(src + off);
  bf16x4_t pk;
  pk[0] = f2b(v.x); pk[1] = f2b(v.y); pk[2] = f2b(v.z); pk[3] = f2b(v.w);
  *(bf16x4_t*)(wb + mat * (512 * 512) + off) = pk;
}

// ---------------- GroupNorm stats: partial sums per (b,g,slice) ----------------
// grid (8, 64): x = slice s (8 channels), y = b*8+g. Deterministic (no atomics).
__global__ __launch_bounds__(256) void gn_stats_kernel(
    const float* __restrict__ x, float2* __restrict__ psum)
{
  const int s = blockIdx.x, bg = blockIdx.y;
  const float* xp = x + ((size_t)bg * CG + s * 8) * N_PIX;   // 8 ch x 1024
  float sum = 0.f, sum2 = 0.f;
#pragma unroll
  for (int it = 0; it < 8; it++) {
    float4 v = ((const float4*)xp)[it * 256 + threadIdx.x];
    sum  += v.x + v.y + v.z + v.w;
    sum2 += v.x * v.x + v.y * v.y + v.z * v.z + v.w * v.w;
  }
#pragma unroll
  for (int off = 32; off; off >>= 1) {
    sum  += __shfl_xor(sum, off, 64);
    sum2 += __shfl_xor(sum2, off, 64);
  }
  __shared__ float red[8];
  const int lane = threadIdx.x & 63, wv = threadIdx.x >> 6;
  if (lane == 0) { red[wv] = sum; red[4 + wv] = sum2; }
  __syncthreads();
  if (threadIdx.x == 0) {
    float s1 = red[0] + red[1] + red[2] + red[3];
    float s2 = red[4] + red[5] + red[6] + red[7];
    psum[bg * 8 + s] = make_float2(s1, s2);
  }
}

// ---------------- GroupNorm apply + transpose -> xnT bf16 [B][N][C] ----------------
// grid (32, 8): x = n-tile (32 pixels), y = b. LDS transpose for coalesced writes.
__global__ __launch_bounds__(256) void gn_apply_kernel(
    const float* __restrict__ x, const float2* __restrict__ psum,
    const float* __restrict__ gw, const float* __restrict__ gb,
    __bf16* __restrict__ xnT)
{
  const int n0 = blockIdx.x * 32, b = blockIdx.y;
  const int tid = threadIdx.x;
  __shared__ float mu_s[8], rs_s[8];
  __shared__ __align__(16) __bf16 tile[32 * 520];

  if (tid < 8) {
    float s1 = 0.f, s2 = 0.f;
#pragma unroll
    for (int i = 0; i < 8; i++) {
      float2 p = psum[(b * 8 + tid) * 8 + i];
      s1 += p.x; s2 += p.y;
    }
    const float inv = 1.f / (float)(CG * N_PIX);
    float mu = s1 * inv;
    float var = s2 * inv - mu * mu;
    mu_s[tid] = mu;
    rs_s[tid] = rsqrtf(var + EPSF);
  }
  __syncthreads();

  const float* xb = x + (size_t)b * C_DIM * N_PIX + n0;
  const int cl = tid >> 3;            // 0..31
  const int nq = (tid & 7) * 4;       // 0,4,...,28
#pragma unroll
  for (int co = 0; co < 16; co++) {
    const int c = co * 32 + cl;
    float4 v = *(const float4*)(xb + (size_t)c * N_PIX + nq);
    const int g = c >> 6;
    const float rs = rs_s[g];
    const float a = rs * gw[c];
    const float bb = gb[c] - mu_s[g] * a;
    tile[(nq + 0) * 520 + c] = f2b(v.x * a + bb);
    tile[(nq + 1) * 520 + c] = f2b(v.y * a + bb);
    tile[(nq + 2) * 520 + c] = f2b(v.z * a + bb);
    tile[(nq + 3) * 520 + c] = f2b(v.w * a + bb);
  }
  __syncthreads();

  __bf16* dst = xnT + ((size_t)b * N_PIX + n0) * C_DIM;
  const int l32 = tid & 31, nr = tid >> 5;   // nr 0..7
#pragma unroll
  for (int no = 0; no < 4; no++) {
    const int n = no * 8 + nr;
#pragma unroll
    for (int co = 0; co < 2; co++) {
      const int c = co * 256 + l32 * 8;
      *(bf16x8_t*)(dst + (size_t)n * C_DIM + c) =
          *(const bf16x8_t*)(tile + n * 520 + c);
    }
  }
}

// ---------------- shared 128x128 gemm_bt core (K=512, lda=ldb=512) ----------------
__device__ __forceinline__ void gemm_core_128(
    const __bf16* __restrict__ A, const __bf16* __restrict__ B,
    __bf16* As, __bf16* Bs, f32x4_t acc[4][4])
{
  const int tid  = threadIdx.x;
  const int lane = tid & 63;
  const int wv   = tid >> 6;
  const int quad = lane >> 4;
  const int l16  = lane & 15;
  const int wm = (wv >> 1) * 64;
  const int wn = (wv & 1) * 64;

  f32x4_t zero = {0.f, 0.f, 0.f, 0.f};
#pragma unroll
  for (int i = 0; i < 4; i++)
#pragma unroll
    for (int j = 0; j < 4; j++) acc[i][j] = zero;

  const int chb0 = wv * 64;
  const int chb1 = 256 + wv * 64;
  const int ch0 = chb0 + lane, ch1 = chb1 + lane;
  const int r0 = ch0 >> 2, k0 = (ch0 & 3) * 8;
  const int r1 = ch1 >> 2, k1 = (ch1 & 3) * 8;

  for (int kt = 0; kt < 512; kt += 32) {
    async16(A + (size_t)r0 * 512 + kt + k0, As + chb0 * 8);
    async16(A + (size_t)r1 * 512 + kt + k1, As + chb1 * 8);
    async16(B + (size_t)r0 * 512 + kt + k0, Bs + chb0 * 8);
    async16(B + (size_t)r1 * 512 + kt + k1, Bs + chb1 * 8);
    __builtin_amdgcn_s_waitcnt(0);
    __syncthreads();
    bf16x8_t af[4], bfr[4];
#pragma unroll
    for (int i = 0; i < 4; i++)
      af[i] = *(const bf16x8_t*)(As + (wm + i * 16 + l16) * 32 + quad * 8);
#pragma unroll
    for (int j = 0; j < 4; j++)
      bfr[j] = *(const bf16x8_t*)(Bs + (wn + j * 16 + l16) * 32 + quad * 8);
#pragma unroll
    for (int i = 0; i < 4; i++)
#pragma unroll
      for (int j = 0; j < 4; j++)
        acc[i][j] = __builtin_amdgcn_mfma_f32_16x16x32_bf16(af[i], bfr[j], acc[i][j], 0, 0, 0);
    __syncthreads();
  }
}

// ---------------- QKV gemm: Q,K -> [b][n][c] bf16 ; V -> [b][c][n] bf16 ----------------
__global__ __launch_bounds__(256) void gemm_qkv_kernel(
    const __bf16* __restrict__ wqkv, const float* __restrict__ qb,
    const float* __restrict__ kb, const float* __restrict__ vb,
    const __bf16* __restrict__ xnT,
    __bf16* __restrict__ qT, __bf16* __restrict__ kT, __bf16* __restrict__ vbuf)
{
  __shared__ __align__(16) __bf16 As[128 * 32];
  __shared__ __align__(16) __bf16 Bs[128 * 32];
  const int z = blockIdx.z, b = z / 3, mat = z % 3;
  const int m0 = blockIdx.y * 128, n0 = blockIdx.x * 128;
  const __bf16* A = wqkv + (size_t)mat * (512 * 512) + (size_t)m0 * 512;
  const __bf16* B = xnT + ((size_t)b * N_PIX + n0) * 512;
  f32x4_t acc[4][4];
  gemm_core_128(A, B, As, Bs, acc);

  const int tid = threadIdx.x, lane = tid & 63, wv = tid >> 6;
  const int quad = lane >> 4, l16 = lane & 15;
  const int wm = (wv >> 1) * 64, wn = (wv & 1) * 64;
  const float* bias = (mat == 0) ? qb : (mat == 1) ? kb : vb;

  if (mat < 2) {
    __bf16* dst = (mat == 0) ? qT : kT;
#pragma unroll
    for (int i = 0; i < 4; i++) {
      const int o = m0 + wm + i * 16 + quad * 4;
      float b0 = bias[o], b1 = bias[o + 1], b2 = bias[o + 2], b3 = bias[o + 3];
#pragma unroll
      for (int j = 0; j < 4; j++) {
        const int n = n0 + wn + j * 16 + l16;
        bf16x4_t pk;
        pk[0] = f2b(acc[i][j][0] + b0);
        pk[1] = f2b(acc[i][j][1] + b1);
        pk[2] = f2b(acc[i][j][2] + b2);
        pk[3] = f2b(acc[i][j][3] + b3);
        *(bf16x4_t*)(dst + ((size_t)b * N_PIX + n) * 512 + o) = pk;
      }
    }
  } else {
#pragma unroll
    for (int i = 0; i < 4; i++) {
      const int o = m0 + wm + i * 16 + quad * 4;
#pragma unroll
      for (int j = 0; j < 4; j++) {
        const int n = n0 + wn + j * 16 + l16;
#pragma unroll
        for (int r = 0; r < 4; r++)
          vbuf[((size_t)b * 512 + o + r) * N_PIX + n] = f2b(acc[i][j][r] + bias[o + r]);
      }
    }
  }
}

// ---------------- flash attention: BQ=64 per block, 4 waves x 16 q-rows ----------------
__global__ __launch_bounds__(256) void attn_kernel(
    const __bf16* __restrict__ qT, const __bf16* __restrict__ kT,
    const __bf16* __restrict__ vbuf, __bf16* __restrict__ aT)
{
  __shared__ __align__(16) __bf16 Qs[64 * 72];
  __shared__ __align__(16) __bf16 Ks[128 * 72];
  __shared__ __align__(16) __bf16 Vs[64 * 136];
  __shared__ __align__(16) __bf16 Ps[64 * 136];
  const int nb = blockIdx.x, h = blockIdx.y, b = blockIdx.z;
  const int tid = threadIdx.x, lane = tid & 63, wv = tid >> 6;
  const int quad = lane >> 4, l16 = lane & 15;
  const int n0 = nb * 64;
  const __bf16* qp = qT + ((size_t)b * N_PIX + n0) * 512 + h * 64;
  const __bf16* kp = kT + ((size_t)b * N_PIX) * 512 + h * 64;
  const __bf16* vp = vbuf + ((size_t)b * 512 + h * 64) * N_PIX;

  for (int cq = tid; cq < 512; cq += 256) {
    int r = cq >> 3, kc = (cq & 7) * 8;
    *(bf16x8_t*)(Qs + r * 72 + kc) = *(const bf16x8_t*)(qp + (size_t)r * 512 + kc);
  }
  __syncthreads();
  bf16x8_t qf[2];
  qf[0] = *(const bf16x8_t*)(Qs + (wv * 16 + l16) * 72 + quad * 8);
  qf[1] = *(const bf16x8_t*)(Qs + (wv * 16 + l16) * 72 + 32 + quad * 8);

  f32x4_t zero = {0.f, 0.f, 0.f, 0.f};
  float mrow[4], lrow[4];
  f32x4_t oacc[4];
#pragma unroll
  for (int r = 0; r < 4; r++) { mrow[r] = -1e30f; lrow[r] = 0.f; }
#pragma unroll
  for (int jc = 0; jc < 4; jc++) oacc[jc] = zero;

  const float scale = 0.125f;

  for (int mt = 0; mt < N_PIX; mt += 128) {
    __syncthreads();
    for (int cq = tid; cq < 1024; cq += 256) {
      int r = cq >> 3, kc = (cq & 7) * 8;
      *(bf16x8_t*)(Ks + r * 72 + kc) = *(const bf16x8_t*)(kp + (size_t)(mt + r) * 512 + kc);
    }
    for (int cv = tid; cv < 1024; cv += 256) {
      int c = cv >> 4, mc = (cv & 15) * 8;
      *(bf16x8_t*)(Vs + c * 136 + mc) = *(const bf16x8_t*)(vp + (size_t)c * N_PIX + mt + mc);
    }
    __syncthreads();

    f32x4_t sacc[8];
#pragma unroll
    for (int j = 0; j < 8; j++) sacc[j] = zero;
#pragma unroll
    for (int j = 0; j < 8; j++) {
      bf16x8_t kf0 = *(const bf16x8_t*)(Ks + (j * 16 + l16) * 72 + quad * 8);
      bf16x8_t kf1 = *(const bf16x8_t*)(Ks + (j * 16 + l16) * 72 + 32 + quad * 8);
      sacc[j] = __builtin_amdgcn_mfma_f32_16x16x32_bf16(qf[0], kf0, sacc[j], 0, 0, 0);
      sacc[j] = __builtin_amdgcn_mfma_f32_16x16x32_bf16(qf[1], kf1, sacc[j], 0, 0, 0);
    }
#pragma unroll
    for (int j = 0; j < 8; j++) sacc[j] *= scale;

    float alpha[4];
#pragma unroll
    for (int r = 0; r < 4; r++) {
      float vm = sacc[0][r];
#pragma unroll
      for (int j = 1; j < 8; j++) vm = fmaxf(vm, sacc[j][r]);
      vm = fmaxf(vm, __shfl_xor(vm, 1, 64));
      vm = fmaxf(vm, __shfl_xor(vm, 2, 64));
      vm = fmaxf(vm, __shfl_xor(vm, 4, 64));
      vm = fmaxf(vm, __shfl_xor(vm, 8, 64));
      float mnew = fmaxf(mrow[r], vm);
      alpha[r] = __expf(mrow[r] - mnew);
      mrow[r] = mnew;
    }
    float rs[4] = {0.f, 0.f, 0.f, 0.f};
#pragma unroll
    for (int j = 0; j < 8; j++) {
#pragma unroll
      for (int r = 0; r < 4; r++) {
        float p = __expf(sacc[j][r] - mrow[r]);
        rs[r] += p;
        Ps[(wv * 16 + quad * 4 + r) * 136 + j * 16 + l16] = f2b(p);
      }
    }
#pragma unroll
    for (int r = 0; r < 4; r++) {
      rs[r] += __shfl_xor(rs[r], 1, 64);
      rs[r] += __shfl_xor(rs[r], 2, 64);
      rs[r] += __shfl_xor(rs[r], 4, 64);
      rs[r] += __shfl_xor(rs[r], 8, 64);
      lrow[r] = lrow[r] * alpha[r] + rs[r];
    }
#pragma unroll
    for (int jc = 0; jc < 4; jc++)
#pragma unroll
      for (int r = 0; r < 4; r++) oacc[jc][r] *= alpha[r];

    asm volatile("s_waitcnt lgkmcnt(0)" ::: "memory");

#pragma unroll
    for (int kk = 0; kk < 4; kk++) {
      bf16x8_t pf = *(const bf16x8_t*)(Ps + (wv * 16 + l16) * 136 + kk * 32 + quad * 8);
#pragma unroll
      for (int jc = 0; jc < 4; jc++) {
        bf16x8_t vf = *(const bf16x8_t*)(Vs + (jc * 16 + l16) * 136 + kk * 32 + quad * 8);
        oacc[jc] = __builtin_amdgcn_mfma_f32_16x16x32_bf16(pf, vf, oacc[jc], 0, 0, 0);
      }
    }
  }

#pragma unroll
  for (int jc = 0; jc < 4; jc++) {
#pragma unroll
    for (int r = 0; r < 4; r++) {
      int n = n0 + wv * 16 + quad * 4 + r;
      int c = h * 64 + jc * 16 + l16;
      aT[((size_t)b * N_PIX + n) * 512 + c] = f2b(oacc[jc][r] / lrow[r]);
    }
  }
}

// ---------------- proj gemm + bias + residual -> fp32 out [b][c][n] ----------------
__global__ __launch_bounds__(256) void gemm_proj_kernel(
    const __bf16* __restrict__ wp, const float* __restrict__ pb,
    const __bf16* __restrict__ aT, const float* __restrict__ x,
    float* __restrict__ out)
{
  __shared__ __align__(16) __bf16 As[128 * 32];
  __shared__ __align__(16) __bf16 Bs[128 * 32];
  const int b = blockIdx.z;
  const int m0 = blockIdx.y * 128, n0 = blockIdx.x * 128;
  const __bf16* A = wp + (size_t)m0 * 512;
  const __bf16* B = aT + ((size_t)b * N_PIX + n0) * 512;
  f32x4_t acc[4][4];
  gemm_core_128(A, B, As, Bs, acc);
  const int tid = threadIdx.x, lane = tid & 63, wv = tid >> 6;
  const int quad = lane >> 4, l16 = lane & 15;
  const int wm = (wv >> 1) * 64, wn = (wv & 1) * 64;
#pragma unroll
  for (int i = 0; i < 4; i++) {
    const int o = m0 + wm + i * 16 + quad * 4;
#pragma unroll
    for (int j = 0; j < 4; j++) {
      const int n = n0 + wn + j * 16 + l16;
#pragma unroll
      for (int r = 0; r < 4; r++) {
        size_t idx = ((size_t)b * 512 + o + r) * N_PIX + n;
        out[idx] = acc[i][j][r] + pb[o + r] + x[idx];
      }
    }
  }
}

extern "C" void kernel_launch(void* const* d_in, const int* in_sizes, int n_in,
                              void* d_out, int out_size, void* d_ws, size_t ws_size,
                              hipStream_t stream)
{
  (void)in_sizes; (void)n_in; (void)out_size; (void)ws_size;
  const float* x   = (const float*)d_in[0];
  const float* gnw = (const float*)d_in[1];
  const float* gnb = (const float*)d_in[2];
  const float* qw  = (const float*)d_in[3];
  const float* qb  = (const float*)d_in[4];
  const float* kw  = (const float*)d_in[5];
  const float* kb  = (const float*)d_in[6];
  const float* vw  = (const float*)d_in[7];
  const float* vb  = (const float*)d_in[8];
  const float* pw  = (const float*)d_in[9];
  const float* pb  = (const float*)d_in[10];
  float* out = (float*)d_out;

  char* ws = (char*)d_ws;
  __bf16* wb   = (__bf16*)(ws);                         // 2 MB
  __bf16* xnT  = (__bf16*)(ws + (size_t)(2  << 20));    // 8 MB
  __bf16* qTb  = (__bf16*)(ws + (size_t)(10 << 20));    // 8 MB
  __bf16* kTb  = (__bf16*)(ws + (size_t)(18 << 20));    // 8 MB
  __bf16* vbf  = (__bf16*)(ws + (size_t)(26 << 20));    // 8 MB
  __bf16* aT   = (__bf16*)(ws + (size_t)(34 << 20));    // 8 MB
  float2* psum = (float2*)(ws + (size_t)(42 << 20));    // 4 KB

  hipLaunchKernelGGL(convert_w_kernel, dim3(1024), dim3(256), 0, stream, qw, kw, vw, pw, wb);
  hipLaunchKernelGGL(gn_stats_kernel, dim3(8, 64), dim3(256), 0, stream, x, psum);
  hipLaunchKernelGGL(gn_apply_kernel, dim3(32, 8), dim3(256), 0, stream, x, psum, gnw, gnb, xnT);
  hipLaunchKernelGGL(gemm_qkv_kernel, dim3(8, 4, 24), dim3(256), 0, stream,
                     wb, qb, kb, vb, xnT, qTb, kTb, vbf);
  hipLaunchKernelGGL(attn_kernel, dim3(16, 8, 8), dim3(256), 0, stream, qTb, kTb, vbf, aT);
  hipLaunchKernelGGL(gemm_proj_kernel, dim3(8, 4, 8), dim3(256), 0, stream,
                     wb + (size_t)3 * 512 * 512, pb, aT, x, out);
}

// Round 4
// 168.153 us; speedup vs baseline: 1.6971x; 1.2849x over previous
//
#include <hip/hip_runtime.h>

#define C_DIM 512
#define N_PIX 1024
#define B_DIM 8
#define NHEAD 8
#define HDIM 64
#define NGRP 8
#define CG 64
#define EPSF 1e-5f

typedef __bf16 bf16x8_t __attribute__((ext_vector_type(8)));
typedef __bf16 bf16x4_t __attribute__((ext_vector_type(4)));
typedef float  f32x4_t  __attribute__((ext_vector_type(4)));

__device__ __forceinline__ __bf16 f2b(float f) {
  unsigned int u = __builtin_bit_cast(unsigned int, f);
  u += 0x7fffu + ((u >> 16) & 1u);
  unsigned short s = (unsigned short)(u >> 16);
  return __builtin_bit_cast(__bf16, s);
}

__device__ __forceinline__ void async16(const void* g, void* l) {
  __builtin_amdgcn_global_load_lds((const __attribute__((address_space(1))) void*)g,
                                   (__attribute__((address_space(3))) void*)l, 16, 0, 0);
}

// ---------------- weight fp32 -> bf16 ----------------
__global__ __launch_bounds__(256) void convert_w_kernel(
    const float* __restrict__ qw, const float* __restrict__ kw,
    const float* __restrict__ vw, const float* __restrict__ pw,
    __bf16* __restrict__ wb)
{
  int idx = blockIdx.x * 256 + threadIdx.x;
  int mat = idx >> 16;
  int off = (idx & 65535) * 4;
  const float* src = (mat == 0) ? qw : (mat == 1) ? kw : (mat == 2) ? vw : pw;
  float4 v = *(const float4*)(src + off);
  bf16x4_t pk;
  pk[0] = f2b(v.x); pk[1] = f2b(v.y); pk[2] = f2b(v.z); pk[3] = f2b(v.w);
  *(bf16x4_t*)(wb + mat * (512 * 512) + off) = pk;
}

// ---------------- GroupNorm stats ----------------
__global__ __launch_bounds__(256) void gn_stats_kernel(
    const float* __restrict__ x, float2* __restrict__ psum)
{
  const int s = blockIdx.x, bg = blockIdx.y;
  const float* xp = x + ((size_t)bg * CG + s * 8) * N_PIX;
  float sum = 0.f, sum2 = 0.f;
#pragma unroll
  for (int it = 0; it < 8; it++) {
    float4 v = ((const float4*)xp)[it * 256 + threadIdx.x];
    sum  += v.x + v.y + v.z + v.w;
    sum2 += v.x * v.x + v.y * v.y + v.z * v.z + v.w * v.w;
  }
#pragma unroll
  for (int off = 32; off; off >>= 1) {
    sum  += __shfl_xor(sum, off, 64);
    sum2 += __shfl_xor(sum2, off, 64);
  }
  __shared__ float red[8];
  const int lane = threadIdx.x & 63, wv = threadIdx.x >> 6;
  if (lane == 0) { red[wv] = sum; red[4 + wv] = sum2; }
  __syncthreads();
  if (threadIdx.x == 0) {
    float s1 = red[0] + red[1] + red[2] + red[3];
    float s2 = red[4] + red[5] + red[6] + red[7];
    psum[bg * 8 + s] = make_float2(s1, s2);
  }
}

// ---------------- GroupNorm apply + transpose -> xnT bf16 [B][N][C] ----------------
__global__ __launch_bounds__(256) void gn_apply_kernel(
    const float* __restrict__ x, const float2* __restrict__ psum,
    const float* __restrict__ gw, const float* __restrict__ gb,
    __bf16* __restrict__ xnT)
{
  const int n0 = blockIdx.x * 32, b = blockIdx.y;
  const int tid = threadIdx.x;
  __shared__ float mu_s[8], rs_s[8];
  __shared__ __align__(16) __bf16 tile[32 * 520];

  if (tid < 8) {
    float s1 = 0.f, s2 = 0.f;
#pragma unroll
    for (int i = 0; i < 8; i++) {
      float2 p = psum[(b * 8 + tid) * 8 + i];
      s1 += p.x; s2 += p.y;
    }
    const float inv = 1.f / (float)(CG * N_PIX);
    float mu = s1 * inv;
    float var = s2 * inv - mu * mu;
    mu_s[tid] = mu;
    rs_s[tid] = rsqrtf(var + EPSF);
  }
  __syncthreads();

  const float* xb = x + (size_t)b * C_DIM * N_PIX + n0;
  const int cl = tid >> 3;
  const int nq = (tid & 7) * 4;
#pragma unroll
  for (int co = 0; co < 16; co++) {
    const int c = co * 32 + cl;
    float4 v = *(const float4*)(xb + (size_t)c * N_PIX + nq);
    const int g = c >> 6;
    const float rs = rs_s[g];
    const float a = rs * gw[c];
    const float bb = gb[c] - mu_s[g] * a;
    tile[(nq + 0) * 520 + c] = f2b(v.x * a + bb);
    tile[(nq + 1) * 520 + c] = f2b(v.y * a + bb);
    tile[(nq + 2) * 520 + c] = f2b(v.z * a + bb);
    tile[(nq + 3) * 520 + c] = f2b(v.w * a + bb);
  }
  __syncthreads();

  __bf16* dst = xnT + ((size_t)b * N_PIX + n0) * C_DIM;
  const int l32 = tid & 31, nr = tid >> 5;
#pragma unroll
  for (int no = 0; no < 4; no++) {
    const int n = no * 8 + nr;
#pragma unroll
    for (int co = 0; co < 2; co++) {
      const int c = co * 256 + l32 * 8;
      *(bf16x8_t*)(dst + (size_t)n * C_DIM + c) =
          *(const bf16x8_t*)(tile + n * 520 + c);
    }
  }
}

// ---------------- shared 128x128 gemm_bt core (K=512) ----------------
__device__ __forceinline__ void gemm_core_128(
    const __bf16* __restrict__ A, const __bf16* __restrict__ B,
    __bf16* As, __bf16* Bs, f32x4_t acc[4][4])
{
  const int tid  = threadIdx.x;
  const int lane = tid & 63;
  const int wv   = tid >> 6;
  const int quad = lane >> 4;
  const int l16  = lane & 15;
  const int wm = (wv >> 1) * 64;
  const int wn = (wv & 1) * 64;

  f32x4_t zero = {0.f, 0.f, 0.f, 0.f};
#pragma unroll
  for (int i = 0; i < 4; i++)
#pragma unroll
    for (int j = 0; j < 4; j++) acc[i][j] = zero;

  const int chb0 = wv * 64;
  const int chb1 = 256 + wv * 64;
  const int ch0 = chb0 + lane, ch1 = chb1 + lane;
  const int r0 = ch0 >> 2, k0 = (ch0 & 3) * 8;
  const int r1 = ch1 >> 2, k1 = (ch1 & 3) * 8;

  for (int kt = 0; kt < 512; kt += 32) {
    async16(A + (size_t)r0 * 512 + kt + k0, As + chb0 * 8);
    async16(A + (size_t)r1 * 512 + kt + k1, As + chb1 * 8);
    async16(B + (size_t)r0 * 512 + kt + k0, Bs + chb0 * 8);
    async16(B + (size_t)r1 * 512 + kt + k1, Bs + chb1 * 8);
    __builtin_amdgcn_s_waitcnt(0);
    __syncthreads();
    bf16x8_t af[4], bfr[4];
#pragma unroll
    for (int i = 0; i < 4; i++)
      af[i] = *(const bf16x8_t*)(As + (wm + i * 16 + l16) * 32 + quad * 8);
#pragma unroll
    for (int j = 0; j < 4; j++)
      bfr[j] = *(const bf16x8_t*)(Bs + (wn + j * 16 + l16) * 32 + quad * 8);
#pragma unroll
    for (int i = 0; i < 4; i++)
#pragma unroll
      for (int j = 0; j < 4; j++)
        acc[i][j] = __builtin_amdgcn_mfma_f32_16x16x32_bf16(af[i], bfr[j], acc[i][j], 0, 0, 0);
    __syncthreads();
  }
}

// ---------------- QKV gemm: Q (pre-scaled 0.125), K -> [b][n][c]; V -> [b][c][n] ----------------
__global__ __launch_bounds__(256) void gemm_qkv_kernel(
    const __bf16* __restrict__ wqkv, const float* __restrict__ qb,
    const float* __restrict__ kb, const float* __restrict__ vb,
    const __bf16* __restrict__ xnT,
    __bf16* __restrict__ qT, __bf16* __restrict__ kT, __bf16* __restrict__ vbuf)
{
  __shared__ __align__(16) __bf16 As[128 * 32];
  __shared__ __align__(16) __bf16 Bs[128 * 32];
  const int z = blockIdx.z, b = z / 3, mat = z % 3;
  const int m0 = blockIdx.y * 128, n0 = blockIdx.x * 128;
  const __bf16* A = wqkv + (size_t)mat * (512 * 512) + (size_t)m0 * 512;
  const __bf16* B = xnT + ((size_t)b * N_PIX + n0) * 512;
  f32x4_t acc[4][4];
  gemm_core_128(A, B, As, Bs, acc);

  const int tid = threadIdx.x, lane = tid & 63, wv = tid >> 6;
  const int quad = lane >> 4, l16 = lane & 15;
  const int wm = (wv >> 1) * 64, wn = (wv & 1) * 64;
  const float* bias = (mat == 0) ? qb : (mat == 1) ? kb : vb;
  const float qscale = (mat == 0) ? 0.125f : 1.0f;   // fold HD^-0.5 into Q

  if (mat < 2) {
    __bf16* dst = (mat == 0) ? qT : kT;
#pragma unroll
    for (int i = 0; i < 4; i++) {
      const int o = m0 + wm + i * 16 + quad * 4;
      float b0 = bias[o], b1 = bias[o + 1], b2 = bias[o + 2], b3 = bias[o + 3];
#pragma unroll
      for (int j = 0; j < 4; j++) {
        const int n = n0 + wn + j * 16 + l16;
        bf16x4_t pk;
        pk[0] = f2b((acc[i][j][0] + b0) * qscale);
        pk[1] = f2b((acc[i][j][1] + b1) * qscale);
        pk[2] = f2b((acc[i][j][2] + b2) * qscale);
        pk[3] = f2b((acc[i][j][3] + b3) * qscale);
        *(bf16x4_t*)(dst + ((size_t)b * N_PIX + n) * 512 + o) = pk;
      }
    }
  } else {
#pragma unroll
    for (int i = 0; i < 4; i++) {
      const int o = m0 + wm + i * 16 + quad * 4;
#pragma unroll
      for (int j = 0; j < 4; j++) {
        const int n = n0 + wn + j * 16 + l16;
#pragma unroll
        for (int r = 0; r < 4; r++)
          vbuf[((size_t)b * 512 + o + r) * N_PIX + n] = f2b(acc[i][j][r] + bias[o + r]);
      }
    }
  }
}

// ---------------- attention: S^T trick, P in registers, no max-tracking ----------------
// Block: 64 q-rows, 4 waves x 16 q. Iterate 16 K/V tiles of 64.
// S^T = K·Q^T (operand swap) -> lane holds P^T at m-slots {mb*16+quad*4+r};
// V A-fragment built with the same slot permutation (two b64 reads) -> PV exact,
// P never leaves registers.
// FIX vs R3: stage the FULL 64-col tile (2 chunks of 8 per thread; R3 wrote only cols 0..31).
__global__ __launch_bounds__(256, 4) void attn_kernel(
    const __bf16* __restrict__ qT, const __bf16* __restrict__ kT,
    const __bf16* __restrict__ vbuf, __bf16* __restrict__ aT)
{
  __shared__ __align__(16) __bf16 Ks[64 * 72];   // K rows m_local, cols c (stride 72)
  __shared__ __align__(16) __bf16 Vs[64 * 68];   // V^T rows c, cols m_local (stride 68)
  const int nb = blockIdx.x, h = blockIdx.y, b = blockIdx.z;
  const int tid = threadIdx.x, lane = tid & 63, wv = tid >> 6;
  const int quad = lane >> 4, l16 = lane & 15;
  const int n0 = nb * 64;

  // Q B-fragment from global (once). q already scaled by 0.125.
  const __bf16* qp = qT + ((size_t)b * N_PIX + n0 + wv * 16 + l16) * 512 + h * 64;
  const bf16x8_t qf0 = *(const bf16x8_t*)(qp + quad * 8);
  const bf16x8_t qf1 = *(const bf16x8_t*)(qp + 32 + quad * 8);

  const __bf16* kp = kT + ((size_t)b * N_PIX) * 512 + h * 64;
  const __bf16* vp = vbuf + ((size_t)b * 512 + h * 64) * N_PIX;

  const int srow = tid >> 2, schk = (tid & 3) * 16;   // 64 rows x 64 cols, 2x16B per thread
  bf16x8_t kreg0 = *(const bf16x8_t*)(kp + (size_t)srow * 512 + schk);
  bf16x8_t kreg1 = *(const bf16x8_t*)(kp + (size_t)srow * 512 + schk + 8);
  bf16x8_t vreg0 = *(const bf16x8_t*)(vp + (size_t)srow * N_PIX + schk);
  bf16x8_t vreg1 = *(const bf16x8_t*)(vp + (size_t)srow * N_PIX + schk + 8);

  const f32x4_t zero = {0.f, 0.f, 0.f, 0.f};
  f32x4_t oacc[4];
#pragma unroll
  for (int jc = 0; jc < 4; jc++) oacc[jc] = zero;
  float lsum = 0.f;

  for (int mt = 0; mt < 16; mt++) {
    __syncthreads();
    *(bf16x8_t*)(Ks + srow * 72 + schk)     = kreg0;
    *(bf16x8_t*)(Ks + srow * 72 + schk + 8) = kreg1;
    *(bf16x8_t*)(Vs + srow * 68 + schk)     = vreg0;
    *(bf16x8_t*)(Vs + srow * 68 + schk + 8) = vreg1;
    __syncthreads();
    if (mt < 15) {   // prefetch next tile (overlaps compute below)
      kreg0 = *(const bf16x8_t*)(kp + (size_t)((mt + 1) * 64 + srow) * 512 + schk);
      kreg1 = *(const bf16x8_t*)(kp + (size_t)((mt + 1) * 64 + srow) * 512 + schk + 8);
      vreg0 = *(const bf16x8_t*)(vp + (size_t)srow * N_PIX + (mt + 1) * 64 + schk);
      vreg1 = *(const bf16x8_t*)(vp + (size_t)srow * N_PIX + (mt + 1) * 64 + schk + 8);
    }

    // S^T tile: 64 m-rows x 16 q-cols per wave
    f32x4_t sacc[4];
#pragma unroll
    for (int mb = 0; mb < 4; mb++) {
      sacc[mb] = zero;
      bf16x8_t kf0 = *(const bf16x8_t*)(Ks + (mb * 16 + l16) * 72 + quad * 8);
      bf16x8_t kf1 = *(const bf16x8_t*)(Ks + (mb * 16 + l16) * 72 + 32 + quad * 8);
      sacc[mb] = __builtin_amdgcn_mfma_f32_16x16x32_bf16(kf0, qf0, sacc[mb], 0, 0, 0);
      sacc[mb] = __builtin_amdgcn_mfma_f32_16x16x32_bf16(kf1, qf1, sacc[mb], 0, 0, 0);
    }

    // p = exp(s); per-lane row-sum partials
    float p[4][4];
#pragma unroll
    for (int mb = 0; mb < 4; mb++)
#pragma unroll
      for (int r = 0; r < 4; r++) {
        p[mb][r] = __expf(sacc[mb][r]);
        lsum += p[mb][r];
      }

    // pack P^T B-fragments directly from registers (slot permutation)
    bf16x8_t pf[2];
#pragma unroll
    for (int pr = 0; pr < 2; pr++)
#pragma unroll
      for (int r = 0; r < 4; r++) {
        pf[pr][r]     = f2b(p[2 * pr][r]);
        pf[pr][4 + r] = f2b(p[2 * pr + 1][r]);
      }

    // O^T += V^T · P^T with matching slot permutation on V
#pragma unroll
    for (int jc = 0; jc < 4; jc++) {
      const int vrow = (jc * 16 + l16) * 68;
#pragma unroll
      for (int pr = 0; pr < 2; pr++) {
        bf16x4_t vlo = *(const bf16x4_t*)(Vs + vrow + pr * 32 + quad * 4);
        bf16x4_t vhi = *(const bf16x4_t*)(Vs + vrow + pr * 32 + 16 + quad * 4);
        bf16x8_t vf;
#pragma unroll
        for (int r = 0; r < 4; r++) { vf[r] = vlo[r]; vf[4 + r] = vhi[r]; }
        oacc[jc] = __builtin_amdgcn_mfma_f32_16x16x32_bf16(vf, pf[pr], oacc[jc], 0, 0, 0);
      }
    }
  }

  // full row-sum: combine the 4 quads holding the same q=l16
  lsum += __shfl_xor(lsum, 16, 64);
  lsum += __shfl_xor(lsum, 32, 64);
  const float inv = 1.f / lsum;

  __bf16* op = aT + ((size_t)b * N_PIX + n0 + wv * 16 + l16) * 512 + h * 64;
#pragma unroll
  for (int jc = 0; jc < 4; jc++) {
    bf16x4_t o4;
#pragma unroll
    for (int r = 0; r < 4; r++) o4[r] = f2b(oacc[jc][r] * inv);
    *(bf16x4_t*)(op + jc * 16 + quad * 4) = o4;
  }
}

// ---------------- proj gemm + bias + residual -> fp32 out [b][c][n] ----------------
__global__ __launch_bounds__(256) void gemm_proj_kernel(
    const __bf16* __restrict__ wp, const float* __restrict__ pb,
    const __bf16* __restrict__ aT, const float* __restrict__ x,
    float* __restrict__ out)
{
  __shared__ __align__(16) __bf16 As[128 * 32];
  __shared__ __align__(16) __bf16 Bs[128 * 32];
  const int b = blockIdx.z;
  const int m0 = blockIdx.y * 128, n0 = blockIdx.x * 128;
  const __bf16* A = wp + (size_t)m0 * 512;
  const __bf16* B = aT + ((size_t)b * N_PIX + n0) * 512;
  f32x4_t acc[4][4];
  gemm_core_128(A, B, As, Bs, acc);
  const int tid = threadIdx.x, lane = tid & 63, wv = tid >> 6;
  const int quad = lane >> 4, l16 = lane & 15;
  const int wm = (wv >> 1) * 64, wn = (wv & 1) * 64;
#pragma unroll
  for (int i = 0; i < 4; i++) {
    const int o = m0 + wm + i * 16 + quad * 4;
#pragma unroll
    for (int j = 0; j < 4; j++) {
      const int n = n0 + wn + j * 16 + l16;
#pragma unroll
      for (int r = 0; r < 4; r++) {
        size_t idx = ((size_t)b * 512 + o + r) * N_PIX + n;
        out[idx] = acc[i][j][r] + pb[o + r] + x[idx];
      }
    }
  }
}

extern "C" void kernel_launch(void* const* d_in, const int* in_sizes, int n_in,
                              void* d_out, int out_size, void* d_ws, size_t ws_size,
                              hipStream_t stream)
{
  (void)in_sizes; (void)n_in; (void)out_size; (void)ws_size;
  const float* x   = (const float*)d_in[0];
  const float* gnw = (const float*)d_in[1];
  const float* gnb = (const float*)d_in[2];
  const float* qw  = (const float*)d_in[3];
  const float* qb  = (const float*)d_in[4];
  const float* kw  = (const float*)d_in[5];
  const float* kb  = (const float*)d_in[6];
  const float* vw  = (const float*)d_in[7];
  const float* vb  = (const float*)d_in[8];
  const float* pw  = (const float*)d_in[9];
  const float* pb  = (const float*)d_in[10];
  float* out = (float*)d_out;

  char* ws = (char*)d_ws;
  __bf16* wb   = (__bf16*)(ws);                         // 2 MB
  __bf16* xnT  = (__bf16*)(ws + (size_t)(2  << 20));    // 8 MB
  __bf16* qTb  = (__bf16*)(ws + (size_t)(10 << 20));    // 8 MB
  __bf16* kTb  = (__bf16*)(ws + (size_t)(18 << 20));    // 8 MB
  __bf16* vbf  = (__bf16*)(ws + (size_t)(26 << 20));    // 8 MB
  __bf16* aT   = (__bf16*)(ws + (size_t)(34 << 20));    // 8 MB
  float2* psum = (float2*)(ws + (size_t)(42 << 20));    // 4 KB

  hipLaunchKernelGGL(convert_w_kernel, dim3(1024), dim3(256), 0, stream, qw, kw, vw, pw, wb);
  hipLaunchKernelGGL(gn_stats_kernel, dim3(8, 64), dim3(256), 0, stream, x, psum);
  hipLaunchKernelGGL(gn_apply_kernel, dim3(32, 8), dim3(256), 0, stream, x, psum, gnw, gnb, xnT);
  hipLaunchKernelGGL(gemm_qkv_kernel, dim3(8, 4, 24), dim3(256), 0, stream,
                     wb, qb, kb, vb, xnT, qTb, kTb, vbf);
  hipLaunchKernelGGL(attn_kernel, dim3(16, 8, 8), dim3(256), 0, stream, qTb, kTb, vbf, aT);
  hipLaunchKernelGGL(gemm_proj_kernel, dim3(8, 4, 8), dim3(256), 0, stream,
                     wb + (size_t)3 * 512 * 512, pb, aT, x, out);
}

// Round 5
// 165.824 us; speedup vs baseline: 1.7209x; 1.0140x over previous
//
#include <hip/hip_runtime.h>

#define C_DIM 512
#define N_PIX 1024
#define B_DIM 8
#define NHEAD 8
#define HDIM 64
#define NGRP 8
#define CG 64
#define EPSF 1e-5f

typedef __bf16 bf16x8_t __attribute__((ext_vector_type(8)));
typedef __bf16 bf16x4_t __attribute__((ext_vector_type(4)));
typedef float  f32x4_t  __attribute__((ext_vector_type(4)));

__device__ __forceinline__ __bf16 f2b(float f) {
  unsigned int u = __builtin_bit_cast(unsigned int, f);
  u += 0x7fffu + ((u >> 16) & 1u);
  unsigned short s = (unsigned short)(u >> 16);
  return __builtin_bit_cast(__bf16, s);
}

__device__ __forceinline__ void async16(const void* g, void* l) {
  __builtin_amdgcn_global_load_lds((const __attribute__((address_space(1))) void*)g,
                                   (__attribute__((address_space(3))) void*)l, 16, 0, 0);
}

// ---------------- prep: weight fp32->bf16 convert (blocks 0..1023) + GN stats (1024..1535) ----------------
__global__ __launch_bounds__(256) void prep_kernel(
    const float* __restrict__ qw, const float* __restrict__ kw,
    const float* __restrict__ vw, const float* __restrict__ pw,
    __bf16* __restrict__ wb,
    const float* __restrict__ x, float2* __restrict__ psum)
{
  if (blockIdx.x < 1024) {
    int idx = blockIdx.x * 256 + threadIdx.x;
    int mat = idx >> 16;
    int off = (idx & 65535) * 4;
    const float* src = (mat == 0) ? qw : (mat == 1) ? kw : (mat == 2) ? vw : pw;
    float4 v = *(const float4*)(src + off);
    bf16x4_t pk;
    pk[0] = f2b(v.x); pk[1] = f2b(v.y); pk[2] = f2b(v.z); pk[3] = f2b(v.w);
    *(bf16x4_t*)(wb + mat * (512 * 512) + off) = pk;
  } else {
    const int t = blockIdx.x - 1024;
    const int s = t & 7, bg = t >> 3;
    const float* xp = x + ((size_t)bg * CG + s * 8) * N_PIX;
    float sum = 0.f, sum2 = 0.f;
#pragma unroll
    for (int it = 0; it < 8; it++) {
      float4 v = ((const float4*)xp)[it * 256 + threadIdx.x];
      sum  += v.x + v.y + v.z + v.w;
      sum2 += v.x * v.x + v.y * v.y + v.z * v.z + v.w * v.w;
    }
#pragma unroll
    for (int off = 32; off; off >>= 1) {
      sum  += __shfl_xor(sum, off, 64);
      sum2 += __shfl_xor(sum2, off, 64);
    }
    __shared__ float red[8];
    const int lane = threadIdx.x & 63, wv = threadIdx.x >> 6;
    if (lane == 0) { red[wv] = sum; red[4 + wv] = sum2; }
    __syncthreads();
    if (threadIdx.x == 0) {
      float s1 = red[0] + red[1] + red[2] + red[3];
      float s2 = red[4] + red[5] + red[6] + red[7];
      psum[bg * 8 + s] = make_float2(s1, s2);
    }
  }
}

// ---------------- GroupNorm apply + transpose -> xnT bf16 [B][N][C] ----------------
__global__ __launch_bounds__(256) void gn_apply_kernel(
    const float* __restrict__ x, const float2* __restrict__ psum,
    const float* __restrict__ gw, const float* __restrict__ gb,
    __bf16* __restrict__ xnT)
{
  const int n0 = blockIdx.x * 32, b = blockIdx.y;
  const int tid = threadIdx.x;
  __shared__ float mu_s[8], rs_s[8];
  __shared__ __align__(16) __bf16 tile[32 * 520];

  if (tid < 8) {
    float s1 = 0.f, s2 = 0.f;
#pragma unroll
    for (int i = 0; i < 8; i++) {
      float2 p = psum[(b * 8 + tid) * 8 + i];
      s1 += p.x; s2 += p.y;
    }
    const float inv = 1.f / (float)(CG * N_PIX);
    float mu = s1 * inv;
    float var = s2 * inv - mu * mu;
    mu_s[tid] = mu;
    rs_s[tid] = rsqrtf(var + EPSF);
  }
  __syncthreads();

  const float* xb = x + (size_t)b * C_DIM * N_PIX + n0;
  const int cl = tid >> 3;
  const int nq = (tid & 7) * 4;
#pragma unroll
  for (int co = 0; co < 16; co++) {
    const int c = co * 32 + cl;
    float4 v = *(const float4*)(xb + (size_t)c * N_PIX + nq);
    const int g = c >> 6;
    const float rs = rs_s[g];
    const float a = rs * gw[c];
    const float bb = gb[c] - mu_s[g] * a;
    tile[(nq + 0) * 520 + c] = f2b(v.x * a + bb);
    tile[(nq + 1) * 520 + c] = f2b(v.y * a + bb);
    tile[(nq + 2) * 520 + c] = f2b(v.z * a + bb);
    tile[(nq + 3) * 520 + c] = f2b(v.w * a + bb);
  }
  __syncthreads();

  __bf16* dst = xnT + ((size_t)b * N_PIX + n0) * C_DIM;
  const int l32 = tid & 31, nr = tid >> 5;
#pragma unroll
  for (int no = 0; no < 4; no++) {
    const int n = no * 8 + nr;
#pragma unroll
    for (int co = 0; co < 2; co++) {
      const int c = co * 256 + l32 * 8;
      *(bf16x8_t*)(dst + (size_t)n * C_DIM + c) =
          *(const bf16x8_t*)(tile + n * 520 + c);
    }
  }
}

// ---------------- shared 128x128 gemm_bt core (K=512) ----------------
__device__ __forceinline__ void gemm_core_128(
    const __bf16* __restrict__ A, const __bf16* __restrict__ B,
    __bf16* As, __bf16* Bs, f32x4_t acc[4][4])
{
  const int tid  = threadIdx.x;
  const int lane = tid & 63;
  const int wv   = tid >> 6;
  const int quad = lane >> 4;
  const int l16  = lane & 15;
  const int wm = (wv >> 1) * 64;
  const int wn = (wv & 1) * 64;

  f32x4_t zero = {0.f, 0.f, 0.f, 0.f};
#pragma unroll
  for (int i = 0; i < 4; i++)
#pragma unroll
    for (int j = 0; j < 4; j++) acc[i][j] = zero;

  const int chb0 = wv * 64;
  const int chb1 = 256 + wv * 64;
  const int ch0 = chb0 + lane, ch1 = chb1 + lane;
  const int r0 = ch0 >> 2, k0 = (ch0 & 3) * 8;
  const int r1 = ch1 >> 2, k1 = (ch1 & 3) * 8;

  for (int kt = 0; kt < 512; kt += 32) {
    async16(A + (size_t)r0 * 512 + kt + k0, As + chb0 * 8);
    async16(A + (size_t)r1 * 512 + kt + k1, As + chb1 * 8);
    async16(B + (size_t)r0 * 512 + kt + k0, Bs + chb0 * 8);
    async16(B + (size_t)r1 * 512 + kt + k1, Bs + chb1 * 8);
    __builtin_amdgcn_s_waitcnt(0);
    __syncthreads();
    bf16x8_t af[4], bfr[4];
#pragma unroll
    for (int i = 0; i < 4; i++)
      af[i] = *(const bf16x8_t*)(As + (wm + i * 16 + l16) * 32 + quad * 8);
#pragma unroll
    for (int j = 0; j < 4; j++)
      bfr[j] = *(const bf16x8_t*)(Bs + (wn + j * 16 + l16) * 32 + quad * 8);
#pragma unroll
    for (int i = 0; i < 4; i++)
#pragma unroll
      for (int j = 0; j < 4; j++)
        acc[i][j] = __builtin_amdgcn_mfma_f32_16x16x32_bf16(af[i], bfr[j], acc[i][j], 0, 0, 0);
    __syncthreads();
  }
}

// ---------------- QKV gemm: grid (8=b, 8=n, 12=mat*4+m) for XCD/L2 locality ----------------
__global__ __launch_bounds__(256) void gemm_qkv_kernel(
    const __bf16* __restrict__ wqkv, const float* __restrict__ qb,
    const float* __restrict__ kb, const float* __restrict__ vb,
    const __bf16* __restrict__ xnT,
    __bf16* __restrict__ qT, __bf16* __restrict__ kT, __bf16* __restrict__ vbuf)
{
  __shared__ __align__(16) __bf16 As[128 * 32];
  __shared__ __align__(16) __bf16 Bs[128 * 32];
  const int b = blockIdx.x;                    // same b -> same linear%8 -> same XCD
  const int n0 = blockIdx.y * 128;
  const int mat = blockIdx.z >> 2;
  const int m0 = (blockIdx.z & 3) * 128;
  const __bf16* A = wqkv + (size_t)mat * (512 * 512) + (size_t)m0 * 512;
  const __bf16* B = xnT + ((size_t)b * N_PIX + n0) * 512;
  f32x4_t acc[4][4];
  gemm_core_128(A, B, As, Bs, acc);

  const int tid = threadIdx.x, lane = tid & 63, wv = tid >> 6;
  const int quad = lane >> 4, l16 = lane & 15;
  const int wm = (wv >> 1) * 64, wn = (wv & 1) * 64;
  const float* bias = (mat == 0) ? qb : (mat == 1) ? kb : vb;
  const float qscale = (mat == 0) ? 0.125f : 1.0f;   // fold HD^-0.5 into Q

  if (mat < 2) {
    __bf16* dst = (mat == 0) ? qT : kT;
#pragma unroll
    for (int i = 0; i < 4; i++) {
      const int o = m0 + wm + i * 16 + quad * 4;
      float b0 = bias[o], b1 = bias[o + 1], b2 = bias[o + 2], b3 = bias[o + 3];
#pragma unroll
      for (int j = 0; j < 4; j++) {
        const int n = n0 + wn + j * 16 + l16;
        bf16x4_t pk;
        pk[0] = f2b((acc[i][j][0] + b0) * qscale);
        pk[1] = f2b((acc[i][j][1] + b1) * qscale);
        pk[2] = f2b((acc[i][j][2] + b2) * qscale);
        pk[3] = f2b((acc[i][j][3] + b3) * qscale);
        *(bf16x4_t*)(dst + ((size_t)b * N_PIX + n) * 512 + o) = pk;
      }
    }
  } else {
#pragma unroll
    for (int i = 0; i < 4; i++) {
      const int o = m0 + wm + i * 16 + quad * 4;
#pragma unroll
      for (int j = 0; j < 4; j++) {
        const int n = n0 + wn + j * 16 + l16;
#pragma unroll
        for (int r = 0; r < 4; r++)
          vbuf[((size_t)b * 512 + o + r) * N_PIX + n] = f2b(acc[i][j][r] + bias[o + r]);
      }
    }
  }
}

// ---------------- attention: grid (64=b*8+h, 16=q-tile) for XCD/L2 K,V reuse ----------------
// S^T = K·Q^T (operand swap) -> lane holds P^T at m-slots {mb*16+quad*4+r};
// V A-fragment built with the same slot permutation -> PV exact, P stays in registers.
__global__ __launch_bounds__(256, 4) void attn_kernel(
    const __bf16* __restrict__ qT, const __bf16* __restrict__ kT,
    const __bf16* __restrict__ vbuf, __bf16* __restrict__ aT)
{
  __shared__ __align__(16) __bf16 Ks[64 * 72];   // K rows m_local, cols c (stride 72)
  __shared__ __align__(16) __bf16 Vs[64 * 68];   // V^T rows c, cols m_local (stride 68)
  const int bh = blockIdx.x;                     // same (b,h) -> same XCD
  const int b = bh >> 3, h = bh & 7;
  const int nb = blockIdx.y;
  const int tid = threadIdx.x, lane = tid & 63, wv = tid >> 6;
  const int quad = lane >> 4, l16 = lane & 15;
  const int n0 = nb * 64;

  const __bf16* qp = qT + ((size_t)b * N_PIX + n0 + wv * 16 + l16) * 512 + h * 64;
  const bf16x8_t qf0 = *(const bf16x8_t*)(qp + quad * 8);
  const bf16x8_t qf1 = *(const bf16x8_t*)(qp + 32 + quad * 8);

  const __bf16* kp = kT + ((size_t)b * N_PIX) * 512 + h * 64;
  const __bf16* vp = vbuf + ((size_t)b * 512 + h * 64) * N_PIX;

  const int srow = tid >> 2, schk = (tid & 3) * 16;   // 64 rows x 64 cols, 2x16B per thread
  bf16x8_t kreg0 = *(const bf16x8_t*)(kp + (size_t)srow * 512 + schk);
  bf16x8_t kreg1 = *(const bf16x8_t*)(kp + (size_t)srow * 512 + schk + 8);
  bf16x8_t vreg0 = *(const bf16x8_t*)(vp + (size_t)srow * N_PIX + schk);
  bf16x8_t vreg1 = *(const bf16x8_t*)(vp + (size_t)srow * N_PIX + schk + 8);

  const f32x4_t zero = {0.f, 0.f, 0.f, 0.f};
  f32x4_t oacc[4];
#pragma unroll
  for (int jc = 0; jc < 4; jc++) oacc[jc] = zero;
  float lsum = 0.f;

  for (int mt = 0; mt < 16; mt++) {
    __syncthreads();
    *(bf16x8_t*)(Ks + srow * 72 + schk)     = kreg0;
    *(bf16x8_t*)(Ks + srow * 72 + schk + 8) = kreg1;
    *(bf16x8_t*)(Vs + srow * 68 + schk)     = vreg0;
    *(bf16x8_t*)(Vs + srow * 68 + schk + 8) = vreg1;
    __syncthreads();
    if (mt < 15) {
      kreg0 = *(const bf16x8_t*)(kp + (size_t)((mt + 1) * 64 + srow) * 512 + schk);
      kreg1 = *(const bf16x8_t*)(kp + (size_t)((mt + 1) * 64 + srow) * 512 + schk + 8);
      vreg0 = *(const bf16x8_t*)(vp + (size_t)srow * N_PIX + (mt + 1) * 64 + schk);
      vreg1 = *(const bf16x8_t*)(vp + (size_t)srow * N_PIX + (mt + 1) * 64 + schk + 8);
    }

    f32x4_t sacc[4];
#pragma unroll
    for (int mb = 0; mb < 4; mb++) {
      sacc[mb] = zero;
      bf16x8_t kf0 = *(const bf16x8_t*)(Ks + (mb * 16 + l16) * 72 + quad * 8);
      bf16x8_t kf1 = *(const bf16x8_t*)(Ks + (mb * 16 + l16) * 72 + 32 + quad * 8);
      sacc[mb] = __builtin_amdgcn_mfma_f32_16x16x32_bf16(kf0, qf0, sacc[mb], 0, 0, 0);
      sacc[mb] = __builtin_amdgcn_mfma_f32_16x16x32_bf16(kf1, qf1, sacc[mb], 0, 0, 0);
    }

    float p[4][4];
#pragma unroll
    for (int mb = 0; mb < 4; mb++)
#pragma unroll
      for (int r = 0; r < 4; r++) {
        p[mb][r] = __expf(sacc[mb][r]);
        lsum += p[mb][r];
      }

    bf16x8_t pf[2];
#pragma unroll
    for (int pr = 0; pr < 2; pr++)
#pragma unroll
      for (int r = 0; r < 4; r++) {
        pf[pr][r]     = f2b(p[2 * pr][r]);
        pf[pr][4 + r] = f2b(p[2 * pr + 1][r]);
      }

#pragma unroll
    for (int jc = 0; jc < 4; jc++) {
      const int vrow = (jc * 16 + l16) * 68;
#pragma unroll
      for (int pr = 0; pr < 2; pr++) {
        bf16x4_t vlo = *(const bf16x4_t*)(Vs + vrow + pr * 32 + quad * 4);
        bf16x4_t vhi = *(const bf16x4_t*)(Vs + vrow + pr * 32 + 16 + quad * 4);
        bf16x8_t vf;
#pragma unroll
        for (int r = 0; r < 4; r++) { vf[r] = vlo[r]; vf[4 + r] = vhi[r]; }
        oacc[jc] = __builtin_amdgcn_mfma_f32_16x16x32_bf16(vf, pf[pr], oacc[jc], 0, 0, 0);
      }
    }
  }

  lsum += __shfl_xor(lsum, 16, 64);
  lsum += __shfl_xor(lsum, 32, 64);
  const float inv = 1.f / lsum;

  __bf16* op = aT + ((size_t)b * N_PIX + n0 + wv * 16 + l16) * 512 + h * 64;
#pragma unroll
  for (int jc = 0; jc < 4; jc++) {
    bf16x4_t o4;
#pragma unroll
    for (int r = 0; r < 4; r++) o4[r] = f2b(oacc[jc][r] * inv);
    *(bf16x4_t*)(op + jc * 16 + quad * 4) = o4;
  }
}

// ---------------- proj gemm + bias + residual: grid (8=b, 8=n, 4=m) ----------------
__global__ __launch_bounds__(256) void gemm_proj_kernel(
    const __bf16* __restrict__ wp, const float* __restrict__ pb,
    const __bf16* __restrict__ aT, const float* __restrict__ x,
    float* __restrict__ out)
{
  __shared__ __align__(16) __bf16 As[128 * 32];
  __shared__ __align__(16) __bf16 Bs[128 * 32];
  const int b = blockIdx.x;
  const int n0 = blockIdx.y * 128;
  const int m0 = blockIdx.z * 128;
  const __bf16* A = wp + (size_t)m0 * 512;
  const __bf16* B = aT + ((size_t)b * N_PIX + n0) * 512;
  f32x4_t acc[4][4];
  gemm_core_128(A, B, As, Bs, acc);
  const int tid = threadIdx.x, lane = tid & 63, wv = tid >> 6;
  const int quad = lane >> 4, l16 = lane & 15;
  const int wm = (wv >> 1) * 64, wn = (wv & 1) * 64;
#pragma unroll
  for (int i = 0; i < 4; i++) {
    const int o = m0 + wm + i * 16 + quad * 4;
#pragma unroll
    for (int j = 0; j < 4; j++) {
      const int n = n0 + wn + j * 16 + l16;
#pragma unroll
      for (int r = 0; r < 4; r++) {
        size_t idx = ((size_t)b * 512 + o + r) * N_PIX + n;
        out[idx] = acc[i][j][r] + pb[o + r] + x[idx];
      }
    }
  }
}

extern "C" void kernel_launch(void* const* d_in, const int* in_sizes, int n_in,
                              void* d_out, int out_size, void* d_ws, size_t ws_size,
                              hipStream_t stream)
{
  (void)in_sizes; (void)n_in; (void)out_size; (void)ws_size;
  const float* x   = (const float*)d_in[0];
  const float* gnw = (const float*)d_in[1];
  const float* gnb = (const float*)d_in[2];
  const float* qw  = (const float*)d_in[3];
  const float* qb  = (const float*)d_in[4];
  const float* kw  = (const float*)d_in[5];
  const float* kb  = (const float*)d_in[6];
  const float* vw  = (const float*)d_in[7];
  const float* vb  = (const float*)d_in[8];
  const float* pw  = (const float*)d_in[9];
  const float* pb  = (const float*)d_in[10];
  float* out = (float*)d_out;

  char* ws = (char*)d_ws;
  __bf16* wb   = (__bf16*)(ws);                         // 2 MB
  __bf16* xnT  = (__bf16*)(ws + (size_t)(2  << 20));    // 8 MB
  __bf16* qTb  = (__bf16*)(ws + (size_t)(10 << 20));    // 8 MB
  __bf16* kTb  = (__bf16*)(ws + (size_t)(18 << 20));    // 8 MB
  __bf16* vbf  = (__bf16*)(ws + (size_t)(26 << 20));    // 8 MB
  __bf16* aT   = (__bf16*)(ws + (size_t)(34 << 20));    // 8 MB
  float2* psum = (float2*)(ws + (size_t)(42 << 20));    // 4 KB

  hipLaunchKernelGGL(prep_kernel, dim3(1536), dim3(256), 0, stream,
                     qw, kw, vw, pw, wb, x, psum);
  hipLaunchKernelGGL(gn_apply_kernel, dim3(32, 8), dim3(256), 0, stream, x, psum, gnw, gnb, xnT);
  hipLaunchKernelGGL(gemm_qkv_kernel, dim3(8, 8, 12), dim3(256), 0, stream,
                     wb, qb, kb, vb, xnT, qTb, kTb, vbf);
  hipLaunchKernelGGL(attn_kernel, dim3(64, 16), dim3(256), 0, stream, qTb, kTb, vbf, aT);
  hipLaunchKernelGGL(gemm_proj_kernel, dim3(8, 8, 4), dim3(256), 0, stream,
                     wb + (size_t)3 * 512 * 512, pb, aT, x, out);
}